// Round 13
// baseline (936.507 us; speedup 1.0000x reference)
//
#include <hip/hip_runtime.h>
#include <stdint.h>

// HeteroSTHN edge-predictor, fused bf16-MFMA.
// R6: row-major LDS B -> 12.4M bank conflicts, 164us. R8: B global->VGPR, latency-bound, 262us.
// R9: 64 rows/wave -> VGPR spill (39MB scratch), 292us. R10: conflict-free fragment-major LDS
// (0.5M conflicts, 128 VGPR, no spill) -> STILL 168us, MfmaUtil 24%. Post-mortem: conflicts were
// never the limiter; the invariant is ~3100cyc/block-interval at 2 waves/SIMD -- the per-wave
// dependent ds_read->MFMA chain has no TLP to hide read latency (m114/m97: 12 waves/CU -> 37%).
// This round: PURE TLP. Same structure, 8 waves/block (P_TILE=256, THREADS=512, grid 512),
// __launch_bounds__(512,4): 2 blocks/CU x 8 waves = 16 waves/CU = 4/SIMD (VGPR stays ~128).

typedef float f32x4 __attribute__((ext_vector_type(4)));
typedef short s16x8 __attribute__((ext_vector_type(8)));

static constexpr int E_NODES = 65536;
static constexpr int D_DIM   = 200;
static constexpr int H_DIM   = 100;
static constexpr int T_TYPES = 8;
static constexpr int NPAD    = 112;   // padded H (7 x 16)
static constexpr int NT      = 7;
static constexpr int KS      = 13;    // K sub-slabs of 32 (merged K: src<200, dst 200..399, pad 416)
static constexpr int P_TILE  = 256;
static constexpr int THREADS = 512;   // 8 waves x 32 rows
static constexpr int REC_B   = 1024;  // bytes per (t,nt,ksg) fragment record
static constexpr int WT_ELEMS = T_TYPES * NT * KS * 512;  // 372736 bf16 = 728 KB
static constexpr int N_GROUPS = 32;                        // 8t x 4 nt-groups {0,1}{2,3}{4,5}{6}
static constexpr int SLAB_MAX_REC = 26;                    // nt-pair slab: 26 recs = 26624 B

__device__ unsigned short g_Wt[WT_ELEMS];   // fragment-major bf16 B image

__device__ __forceinline__ unsigned short f2bf(float f) {
  unsigned int u = __float_as_uint(f);
  u += 0x7FFFu + ((u >> 16) & 1u);   // round-to-nearest-even
  return (unsigned short)(u >> 16);
}

__global__ void prep_weights(const float* __restrict__ srcW, const float* __restrict__ dstW) {
  int idx = blockIdx.x * blockDim.x + threadIdx.x;
  if (idx >= WT_ELEMS) return;
  // element = rec*512 + lane*8 + e ; rec = (t*7 + nt)*13 + ksg   (nt-major for slab contiguity)
  int e   = idx & 7;
  int l   = (idx >> 3) & 63;
  int rec = idx >> 9;
  int ksg = rec % 13;
  int r2  = rec / 13;
  int nt  = r2 % 7;
  int t   = r2 / 7;
  int j   = nt * 16 + (l & 15);             // B col (H dim)
  int k   = ksg * 32 + ((l >> 4) << 3) + e; // merged K
  float v = 0.0f;
  if (j < H_DIM) {
    if (k < D_DIM)          v = srcW[(t * D_DIM + k) * H_DIM + j];
    else if (k < 2 * D_DIM) v = dstW[(t * D_DIM + (k - D_DIM)) * H_DIM + j];
  }
  g_Wt[idx] = f2bf(v);
}

// linear DMA copy of nrec 1024B records into LDS
__device__ __forceinline__ void stage(int rec0, int nrec, unsigned short* dst, int tid) {
  const char* src = (const char*)g_Wt + (size_t)rec0 * REC_B;
  char* d = (char*)dst;
  const int xf = nrec * 64;   // 16B transfers
#pragma unroll
  for (int i = 0; i < 4; ++i) {   // covers up to 2048 xfers (26 recs = 1664)
    const int idx = i * THREADS + tid;
    if (idx < xf) {
      __builtin_amdgcn_global_load_lds(
          (const __attribute__((address_space(1))) void*)(src + idx * 16),
          (__attribute__((address_space(3))) void*)(d + idx * 16),
          16, 0, 0);
    }
  }
}

__global__ __launch_bounds__(THREADS, 4)
void fused_pred(const float* __restrict__ h,
                const float* __restrict__ srcB, const float* __restrict__ dstB,
                const float* __restrict__ outW, const float* __restrict__ outB,
                const int* __restrict__ poss, float* __restrict__ out) {
  __shared__ __align__(16) unsigned short ldsB[2][SLAB_MAX_REC * 512];  // 2 x 26624 B
  __shared__ __align__(16) int ldsMask[P_TILE * T_TYPES];               // 8 KB
  __shared__ float ldsBias[T_TYPES * NPAD];                             // 3.5 KB
  __shared__ float ldsOutw[T_TYPES * NPAD];                             // 3.5 KB
  __shared__ float ldsOutb[T_TYPES];

  const int tid  = threadIdx.x;
  const int lane = tid & 63;
  const int w    = tid >> 6;       // wave 0..7, owns rows [32w, 32w+32)
  const int c    = lane & 15;
  const int g    = lane >> 4;

  // XCD-paired remap: pos/neg tiles over the same src rows adjacent per-XCD.
  const int l     = ((int)blockIdx.x & 7) * 64 + ((int)blockIdx.x >> 3);
  const int which = l & 1;
  const int grp   = l >> 1;
  const int P0    = which * E_NODES + grp * P_TILE;

  // first slab (t0, nt{0,1}) in flight under the whole prologue
  stage(0, SLAB_MAX_REC, ldsB[0], tid);
  __builtin_amdgcn_sched_barrier(0);

  // constants + mask -> LDS
  {
    int idx = tid;
    if (idx < T_TYPES * NPAD) {
      int t = idx / NPAD, j = idx - t * NPAD;
      float bb = 0.f, ww = 0.f;
      if (j < H_DIM) {
        bb = srcB[t * H_DIM + j] + dstB[t * H_DIM + j];
        ww = outW[t * H_DIM + j];
      }
      ldsBias[idx] = bb;
      ldsOutw[idx] = ww;
    }
    idx = tid + THREADS;
    if (idx < T_TYPES * NPAD) {
      int t = idx / NPAD, j = idx - t * NPAD;
      float bb = 0.f, ww = 0.f;
      if (j < H_DIM) {
        bb = srcB[t * H_DIM + j] + dstB[t * H_DIM + j];
        ww = outW[t * H_DIM + j];
      }
      ldsBias[idx] = bb;
      ldsOutw[idx] = ww;
    }
  }
  if (tid < T_TYPES) ldsOutb[tid] = outB[tid];
  ((int4*)ldsMask)[tid] = ((const int4*)(poss + (size_t)P0 * T_TYPES))[tid];  // 512 int4 = 256x8

  // A fragments in registers: A[mt][ks], merged K, k = ks*32 + g*8 + e; 32 rows/wave
  s16x8 A[2][KS];
#pragma unroll
  for (int mt = 0; mt < 2; ++mt) {
    const int row = w * 32 + mt * 16 + c;
    const int p   = P0 + row;
    const float* sp = h + (size_t)(p & (E_NODES - 1)) * D_DIM;
    const float* dp = h + ((size_t)E_NODES + (size_t)p) * D_DIM;
#pragma unroll
    for (int ks = 0; ks < KS; ++ks) {
      const int k0 = ks * 32 + g * 8;
      s16x8 a = {};
      if (k0 < 2 * D_DIM) {                 // only ks=12, g>=2 is pad
        const float* base = (k0 < D_DIM) ? (sp + k0) : (dp + (k0 - D_DIM));
        float4 f0 = *(const float4*)(base);
        float4 f1 = *(const float4*)(base + 4);
        a[0] = (short)f2bf(f0.x); a[1] = (short)f2bf(f0.y);
        a[2] = (short)f2bf(f0.z); a[3] = (short)f2bf(f0.w);
        a[4] = (short)f2bf(f1.x); a[5] = (short)f2bf(f1.y);
        a[6] = (short)f2bf(f1.z); a[7] = (short)f2bf(f1.w);
      }
      A[mt][ks] = a;
    }
  }

  const f32x4 ZERO4 = {0.f, 0.f, 0.f, 0.f};
  f32x4 v0 = ZERO4, v1 = ZERO4;        // per-t running sum_j relu(.)*w_j  (mt=0,1)
  float runmax[2][4];
#pragma unroll
  for (int mt = 0; mt < 2; ++mt)
#pragma unroll
    for (int r = 0; r < 4; ++r) runmax[mt][r] = -1e30f;

  __syncthreads();   // slab 0 staged, constants/mask visible

  int buf = 0;
  for (int t = 0; t < T_TYPES; ++t) {
#pragma unroll
    for (int ng = 0; ng < 4; ++ng) {
      const int gidx = t * 4 + ng;
      // issue next slab first: latency hides under this interval's compute
      if (gidx + 1 < N_GROUPS) {
        const int t1  = (gidx + 1) >> 2;
        const int ng1 = (gidx + 1) & 3;
        stage((t1 * 7 + ng1 * 2) * 13, (ng1 < 3) ? 26 : 13, ldsB[buf ^ 1], tid);
      }
      __builtin_amdgcn_sched_barrier(0);

      const char* B = (const char*)ldsB[buf] + lane * 16;
      const int NL = (ng < 3) ? 2 : 1;
#pragma unroll
      for (int nl = 0; nl < 2; ++nl) {
        if (nl < NL) {
          const int nt = ng * 2 + nl;
          const float bj = ldsBias[t * NPAD + nt * 16 + c];
          const float wj = ldsOutw[t * NPAD + nt * 16 + c];
          f32x4 acc0 = ZERO4, acc1 = ZERO4;
#pragma unroll
          for (int ksg = 0; ksg < KS; ++ksg) {
            s16x8 b = *(const s16x8*)(B + (nl * 13 + ksg) * REC_B);
            acc0 = __builtin_amdgcn_mfma_f32_16x16x32_bf16(A[0][ksg], b, acc0, 0, 0, 0);
            acc1 = __builtin_amdgcn_mfma_f32_16x16x32_bf16(A[1][ksg], b, acc1, 0, 0, 0);
          }
#pragma unroll
          for (int r = 0; r < 4; ++r) {
            v0[r] += fmaxf(acc0[r] + bj, 0.f) * wj;
            v1[r] += fmaxf(acc1[r] + bj, 0.f) * wj;
          }
        }
      }

      if (ng == 3) {
        // finalize t: 16-lane reduce of v over c, +out_b, masked running max
        const float ob = ldsOutb[t];
#pragma unroll
        for (int mt = 0; mt < 2; ++mt) {
#pragma unroll
          for (int r = 0; r < 4; ++r) {
            float vv = (mt == 0) ? v0[r] : v1[r];
            vv += __shfl_xor(vv, 1);
            vv += __shfl_xor(vv, 2);
            vv += __shfl_xor(vv, 4);
            vv += __shfl_xor(vv, 8);
            const float pred = vv + ob;
            const int row = w * 32 + mt * 16 + g * 4 + r;   // C/D: row=(lane>>4)*4+reg, col=lane&15
            if (ldsMask[row * T_TYPES + t] != 0)
              runmax[mt][r] = fmaxf(runmax[mt][r], pred);
          }
        }
        v0 = ZERO4; v1 = ZERO4;
      }

      __syncthreads();   // drains the issued stage; all waves done with ldsB[buf]
      buf ^= 1;
    }
  }

  if (c == 0) {
#pragma unroll
    for (int mt = 0; mt < 2; ++mt)
#pragma unroll
      for (int r = 0; r < 4; ++r) {
        const int row = w * 32 + mt * 16 + g * 4 + r;
        const float v = runmax[mt][r];
        out[P0 + row] = (v > -1e29f) ? v : 0.0f;   // where(any_valid, best, 0)
      }
  }
}

extern "C" void kernel_launch(void* const* d_in, const int* in_sizes, int n_in,
                              void* d_out, int out_size, void* d_ws, size_t ws_size,
                              hipStream_t stream) {
  const float* h    = (const float*)d_in[0];
  const float* srcW = (const float*)d_in[1];
  const float* srcB = (const float*)d_in[2];
  const float* dstW = (const float*)d_in[3];
  const float* dstB = (const float*)d_in[4];
  const float* outW = (const float*)d_in[5];
  const float* outB = (const float*)d_in[6];
  const int*   poss = (const int*)d_in[7];
  float* out = (float*)d_out;

  prep_weights<<<(WT_ELEMS + 255) / 256, 256, 0, stream>>>(srcW, dstW);

  const int nblocks = (2 * E_NODES) / P_TILE;   // 512
  fused_pred<<<nblocks, THREADS, 0, stream>>>(h, srcB, dstB, outW, outB, poss, out);
}

// Round 14
// 345.239 us; speedup vs baseline: 2.7126x; 2.7126x over previous
//
#include <hip/hip_runtime.h>
#include <stdint.h>

// HeteroSTHN edge-predictor, fused bf16-MFMA.
// R6: row-major LDS B -> bank conflicts, 164us. R8: B global->VGPR, latency-bound, 262us.
// R9: 64 rows/wave -> spill, 292us. R10: conflict-free fragment-major LDS, VGPR=128, no
// spill -> 168us @ 2 waves/SIMD (LDS 65KB -> 2 blocks/CU was the occupancy limiter).
// R13: __launch_bounds__(512,4) made the compiler cap VGPR=64 -> wholesale spill (696MB
// scratch writes, 748us). Lesson: don't force occupancy via launch_bounds; cap LDS instead.
// This round: EXACT round-10 per-thread code (proven VGPR=128 under launch_bounds(256,2))
// with single-nt slabs (13 recs = 13.3KB, dbuf 26.6KB; total LDS ~37.9KB) -> 4 blocks/CU
// co-resident at runtime = 16 waves/CU = 4 waves/SIMD. Grid 1024 = full residency.

typedef float f32x4 __attribute__((ext_vector_type(4)));
typedef short s16x8 __attribute__((ext_vector_type(8)));

static constexpr int E_NODES = 65536;
static constexpr int D_DIM   = 200;
static constexpr int H_DIM   = 100;
static constexpr int T_TYPES = 8;
static constexpr int NPAD    = 112;   // padded H (7 x 16)
static constexpr int NT      = 7;
static constexpr int KS      = 13;    // K sub-slabs of 32 (merged K: src<200, dst 200..399, pad 416)
static constexpr int P_TILE  = 128;
static constexpr int THREADS = 256;   // 4 waves x 32 rows
static constexpr int REC_B   = 1024;  // bytes per (t,nt,ksg) fragment record
static constexpr int WT_ELEMS = T_TYPES * NT * KS * 512;  // 372736 bf16 = 728 KB
static constexpr int N_GROUPS = 56;                        // 8t x 7nt single-nt slabs
static constexpr int SLAB_REC = 13;                        // 13 recs = 13312 B per slab

__device__ unsigned short g_Wt[WT_ELEMS];   // fragment-major bf16 B image

__device__ __forceinline__ unsigned short f2bf(float f) {
  unsigned int u = __float_as_uint(f);
  u += 0x7FFFu + ((u >> 16) & 1u);   // round-to-nearest-even
  return (unsigned short)(u >> 16);
}

__global__ void prep_weights(const float* __restrict__ srcW, const float* __restrict__ dstW) {
  int idx = blockIdx.x * blockDim.x + threadIdx.x;
  if (idx >= WT_ELEMS) return;
  // element = rec*512 + lane*8 + e ; rec = (t*7 + nt)*13 + ksg   (nt-major: slab = 13 contiguous recs)
  int e   = idx & 7;
  int l   = (idx >> 3) & 63;
  int rec = idx >> 9;
  int ksg = rec % 13;
  int r2  = rec / 13;
  int nt  = r2 % 7;
  int t   = r2 / 7;
  int j   = nt * 16 + (l & 15);             // B col (H dim)
  int k   = ksg * 32 + ((l >> 4) << 3) + e; // merged K
  float v = 0.0f;
  if (j < H_DIM) {
    if (k < D_DIM)          v = srcW[(t * D_DIM + k) * H_DIM + j];
    else if (k < 2 * D_DIM) v = dstW[(t * D_DIM + (k - D_DIM)) * H_DIM + j];
  }
  g_Wt[idx] = f2bf(v);
}

// linear DMA copy of one 13-rec slab (832 x 16B transfers) into LDS
__device__ __forceinline__ void stage(int rec0, unsigned short* dst, int tid) {
  const char* src = (const char*)g_Wt + (size_t)rec0 * REC_B;
  char* d = (char*)dst;
  const int xf = SLAB_REC * 64;   // 832
#pragma unroll
  for (int i = 0; i < 4; ++i) {
    const int idx = i * THREADS + tid;
    if (idx < xf) {
      __builtin_amdgcn_global_load_lds(
          (const __attribute__((address_space(1))) void*)(src + idx * 16),
          (__attribute__((address_space(3))) void*)(d + idx * 16),
          16, 0, 0);
    }
  }
}

__global__ __launch_bounds__(THREADS, 2)
void fused_pred(const float* __restrict__ h,
                const float* __restrict__ srcB, const float* __restrict__ dstB,
                const float* __restrict__ outW, const float* __restrict__ outB,
                const int* __restrict__ poss, float* __restrict__ out) {
  __shared__ __align__(16) unsigned short ldsB[2][SLAB_REC * 512];  // 2 x 13312 B
  __shared__ __align__(16) int ldsMask[P_TILE * T_TYPES];           // 4 KB
  __shared__ float ldsBias[T_TYPES * NPAD];                         // 3.5 KB
  __shared__ float ldsOutw[T_TYPES * NPAD];                         // 3.5 KB
  __shared__ float ldsOutb[T_TYPES];

  const int tid  = threadIdx.x;
  const int lane = tid & 63;
  const int w    = tid >> 6;       // wave 0..3, owns rows [32w, 32w+32)
  const int c    = lane & 15;
  const int g    = lane >> 4;

  // XCD-paired remap: pos/neg tiles over the same src rows adjacent per-XCD.
  const int l     = ((int)blockIdx.x & 7) * 128 + ((int)blockIdx.x >> 3);
  const int which = l & 1;
  const int grp   = l >> 1;
  const int P0    = which * E_NODES + grp * P_TILE;

  // first slab (t0, nt0) in flight under the whole prologue
  stage(0, ldsB[0], tid);
  __builtin_amdgcn_sched_barrier(0);

  // constants + mask -> LDS
#pragma unroll
  for (int i = 0; i < 4; ++i) {
    int idx = i * THREADS + tid;
    if (idx < T_TYPES * NPAD) {
      int t = idx / NPAD, j = idx - t * NPAD;
      float bb = 0.f, ww = 0.f;
      if (j < H_DIM) {
        bb = srcB[t * H_DIM + j] + dstB[t * H_DIM + j];
        ww = outW[t * H_DIM + j];
      }
      ldsBias[idx] = bb;
      ldsOutw[idx] = ww;
    }
  }
  if (tid < T_TYPES) ldsOutb[tid] = outB[tid];
  ((int4*)ldsMask)[tid] = ((const int4*)(poss + (size_t)P0 * T_TYPES))[tid];  // 256 int4 = 128x8

  // A fragments in registers: A[mt][ks], merged K, k = ks*32 + g*8 + e; 32 rows/wave
  s16x8 A[2][KS];
#pragma unroll
  for (int mt = 0; mt < 2; ++mt) {
    const int row = w * 32 + mt * 16 + c;
    const int p   = P0 + row;
    const float* sp = h + (size_t)(p & (E_NODES - 1)) * D_DIM;
    const float* dp = h + ((size_t)E_NODES + (size_t)p) * D_DIM;
#pragma unroll
    for (int ks = 0; ks < KS; ++ks) {
      const int k0 = ks * 32 + g * 8;
      s16x8 a = {};
      if (k0 < 2 * D_DIM) {                 // only ks=12, g>=2 is pad
        const float* base = (k0 < D_DIM) ? (sp + k0) : (dp + (k0 - D_DIM));
        float4 f0 = *(const float4*)(base);
        float4 f1 = *(const float4*)(base + 4);
        a[0] = (short)f2bf(f0.x); a[1] = (short)f2bf(f0.y);
        a[2] = (short)f2bf(f0.z); a[3] = (short)f2bf(f0.w);
        a[4] = (short)f2bf(f1.x); a[5] = (short)f2bf(f1.y);
        a[6] = (short)f2bf(f1.z); a[7] = (short)f2bf(f1.w);
      }
      A[mt][ks] = a;
    }
  }

  const f32x4 ZERO4 = {0.f, 0.f, 0.f, 0.f};
  f32x4 v0 = ZERO4, v1 = ZERO4;        // per-t running sum_j relu(.)*w_j  (mt=0,1)
  float runmax[2][4];
#pragma unroll
  for (int mt = 0; mt < 2; ++mt)
#pragma unroll
    for (int r = 0; r < 4; ++r) runmax[mt][r] = -1e30f;

  __syncthreads();   // slab 0 staged, constants/mask visible

  int buf = 0;
  for (int t = 0; t < T_TYPES; ++t) {
#pragma unroll
    for (int nt = 0; nt < NT; ++nt) {
      const int gidx = t * NT + nt;
      // issue next slab first: latency hides under this interval's compute
      if (gidx + 1 < N_GROUPS) stage((gidx + 1) * SLAB_REC, ldsB[buf ^ 1], tid);
      __builtin_amdgcn_sched_barrier(0);

      const char* B = (const char*)ldsB[buf] + lane * 16;
      const float bj = ldsBias[t * NPAD + nt * 16 + c];
      const float wj = ldsOutw[t * NPAD + nt * 16 + c];
      f32x4 acc0 = ZERO4, acc1 = ZERO4;
#pragma unroll
      for (int ksg = 0; ksg < KS; ++ksg) {
        s16x8 b = *(const s16x8*)(B + ksg * REC_B);
        acc0 = __builtin_amdgcn_mfma_f32_16x16x32_bf16(A[0][ksg], b, acc0, 0, 0, 0);
        acc1 = __builtin_amdgcn_mfma_f32_16x16x32_bf16(A[1][ksg], b, acc1, 0, 0, 0);
      }
#pragma unroll
      for (int r = 0; r < 4; ++r) {
        v0[r] += fmaxf(acc0[r] + bj, 0.f) * wj;
        v1[r] += fmaxf(acc1[r] + bj, 0.f) * wj;
      }

      if (nt == NT - 1) {
        // finalize t: 16-lane reduce of v over c, +out_b, masked running max
        const float ob = ldsOutb[t];
#pragma unroll
        for (int mt = 0; mt < 2; ++mt) {
#pragma unroll
          for (int r = 0; r < 4; ++r) {
            float vv = (mt == 0) ? v0[r] : v1[r];
            vv += __shfl_xor(vv, 1);
            vv += __shfl_xor(vv, 2);
            vv += __shfl_xor(vv, 4);
            vv += __shfl_xor(vv, 8);
            const float pred = vv + ob;
            const int row = w * 32 + mt * 16 + g * 4 + r;   // C/D: row=(lane>>4)*4+reg, col=lane&15
            if (ldsMask[row * T_TYPES + t] != 0)
              runmax[mt][r] = fmaxf(runmax[mt][r], pred);
          }
        }
        v0 = ZERO4; v1 = ZERO4;
      }

      __syncthreads();   // drains the issued stage; all waves done with ldsB[buf]
      buf ^= 1;
    }
  }

  if (c == 0) {
#pragma unroll
    for (int mt = 0; mt < 2; ++mt)
#pragma unroll
      for (int r = 0; r < 4; ++r) {
        const int row = w * 32 + mt * 16 + g * 4 + r;
        const float v = runmax[mt][r];
        out[P0 + row] = (v > -1e29f) ? v : 0.0f;   // where(any_valid, best, 0)
      }
  }
}

extern "C" void kernel_launch(void* const* d_in, const int* in_sizes, int n_in,
                              void* d_out, int out_size, void* d_ws, size_t ws_size,
                              hipStream_t stream) {
  const float* h    = (const float*)d_in[0];
  const float* srcW = (const float*)d_in[1];
  const float* srcB = (const float*)d_in[2];
  const float* dstW = (const float*)d_in[3];
  const float* dstB = (const float*)d_in[4];
  const float* outW = (const float*)d_in[5];
  const float* outB = (const float*)d_in[6];
  const int*   poss = (const int*)d_in[7];
  float* out = (float*)d_out;

  prep_weights<<<(WT_ELEMS + 255) / 256, 256, 0, stream>>>(srcW, dstW);

  const int nblocks = (2 * E_NODES) / P_TILE;   // 1024
  fused_pred<<<nblocks, THREADS, 0, stream>>>(h, srcB, dstB, outW, outB, poss, out);
}